// Round 1
// baseline (412.685 us; speedup 1.0000x reference)
//
#include <hip/hip_runtime.h>
#include <stdint.h>
#include <stddef.h>

#define DM 1024
#define NH 16
#define DKh 64
#define Bb 2
#define Ss 2048
#define Mm 4096   // Bb*Ss

typedef unsigned short u16;
typedef __attribute__((ext_vector_type(8))) short short8;
typedef __attribute__((ext_vector_type(4))) float f32x4;

typedef const __attribute__((address_space(1))) void gvoid_t;
typedef __attribute__((address_space(3))) void lvoid_t;

__device__ __forceinline__ void gload16(const void* g, void* l) {
  __builtin_amdgcn_global_load_lds((gvoid_t*)g, (lvoid_t*)l, 16, 0, 0);
}

__device__ __forceinline__ u16 f2bf(float x) {
  unsigned u = __float_as_uint(x);
  unsigned r = (u + 0x7FFFu + ((u >> 16) & 1u)) >> 16;
  return (u16)r;
}

// ---------------- RoPE table: cos/sin of s * 10000^(-d/32), (2048 x 32) ----
__global__ void rope_kernel(float* __restrict__ ct, float* __restrict__ st) {
  int t = blockIdx.x * blockDim.x + threadIdx.x;   // 65536
  int s = t >> 5, d = t & 31;
  float inv = expf(-(float)d * (9.210340371976184f / 32.0f)); // ln(10000)/32
  float a = (float)s * inv;
  ct[t] = cosf(a);
  st[t] = sinf(a);
}

// ---------------- fp32 -> bf16 conversion (float4 vectorized) --------------
__global__ void cvt_kernel(const float* __restrict__ src, u16* __restrict__ dst, int n4) {
  int i = blockIdx.x * blockDim.x + threadIdx.x;
  if (i >= n4) return;
  float4 v = ((const float4*)src)[i];
  ushort4 o;
  o.x = f2bf(v.x); o.y = f2bf(v.y); o.z = f2bf(v.z); o.w = f2bf(v.w);
  ((ushort4*)dst)[i] = o;
}

// ---------------- 128x128 bf16 MFMA GEMM body ------------------------------
// C[m,n] = sum_k A[m,k] * W[n,k]   (A: Mx1024 row-major, W: 1024x1024 row-major)
// MODE 0: bf16 out to (B,H,S,dk) with RoPE; MODE 1: same, no RoPE; MODE 2: fp32 row-major out.
template <int MODE>
__device__ void gemm128_dev(u16* At, u16* Bt,
                            const u16* __restrict__ A, const u16* __restrict__ W,
                            void* __restrict__ O,
                            const float* __restrict__ ct, const float* __restrict__ st) {
  const int tid = threadIdx.x, lane = tid & 63, wid = tid >> 6;
  const int tm = blockIdx.x >> 3, tn = blockIdx.x & 7;
  const int wr = wid >> 1, wc = wid & 1;
  const int lg = lane >> 4, lr16 = lane & 15;
  const f32x4 zero = {0.f, 0.f, 0.f, 0.f};
  f32x4 acc[4][4];
#pragma unroll
  for (int a = 0; a < 4; a++)
#pragma unroll
    for (int b = 0; b < 4; b++) acc[a][b] = zero;

  const u16* Ab = A + (size_t)tm * 128 * DM;
  const u16* Wb = W + (size_t)tn * 128 * DM;

  for (int kt = 0; kt < 16; kt++) {
    const int k0 = kt * 64;
    // stage A and W tiles: [128][64] bf16, 16B-slot XOR swizzle (slot ^= row&7)
#pragma unroll
    for (int c = 0; c < 4; c++) {
      int e = (c * 256 + tid) * 8;
      int row = e >> 6, slot = (e >> 3) & 7;
      int ss = slot ^ (row & 7);
      gload16(Ab + (size_t)row * DM + k0 + ss * 8, &At[(c * 256 + wid * 64) * 8]);
    }
#pragma unroll
    for (int c = 0; c < 4; c++) {
      int e = (c * 256 + tid) * 8;
      int row = e >> 6, slot = (e >> 3) & 7;
      int ss = slot ^ (row & 7);
      gload16(Wb + (size_t)row * DM + k0 + ss * 8, &Bt[(c * 256 + wid * 64) * 8]);
    }
    __syncthreads();
#pragma unroll
    for (int kk = 0; kk < 2; kk++) {
      short8 af[4], bfr[4];
#pragma unroll
      for (int mi = 0; mi < 4; mi++) {
        int row = wr * 64 + mi * 16 + lr16;
        int ps = (kk * 4 + lg) ^ (row & 7);
        af[mi] = *(const short8*)&At[row * 64 + ps * 8];
      }
#pragma unroll
      for (int ni = 0; ni < 4; ni++) {
        int row = wc * 64 + ni * 16 + lr16;
        int ps = (kk * 4 + lg) ^ (row & 7);
        bfr[ni] = *(const short8*)&Bt[row * 64 + ps * 8];
      }
#pragma unroll
      for (int mi = 0; mi < 4; mi++)
#pragma unroll
        for (int ni = 0; ni < 4; ni++)
          acc[mi][ni] = __builtin_amdgcn_mfma_f32_16x16x32_bf16(af[mi], bfr[ni], acc[mi][ni], 0, 0, 0);
    }
    __syncthreads();
  }

  // epilogue. C layout: col = lane&15, row = (lane>>4)*4 + i
  if (MODE == 2) {
    float* Out = (float*)O;
#pragma unroll
    for (int mi = 0; mi < 4; mi++)
#pragma unroll
      for (int i = 0; i < 4; i++) {
        int m = tm * 128 + wr * 64 + mi * 16 + lg * 4 + i;
        float* orow = Out + (size_t)m * DM + tn * 128 + wc * 64;
#pragma unroll
        for (int ni = 0; ni < 4; ni++) orow[ni * 16 + lr16] = acc[mi][ni][i];
      }
  } else {
    u16* Out = (u16*)O;
    const int h = tn * 2 + wc;  // head index (64-wide wave block == one head)
#pragma unroll
    for (int mi = 0; mi < 4; mi++)
#pragma unroll
      for (int i = 0; i < 4; i++) {
        int m = tm * 128 + wr * 64 + mi * 16 + lg * 4 + i;
        int b = m >> 11, s = m & 2047;
        u16* ob = Out + (((size_t)(b * NH + h)) * Ss + s) * DKh;
        if (MODE == 0) {
#pragma unroll
          for (int ni = 0; ni < 2; ni++) {
            int d = ni * 16 + lr16;  // in [0,32)
            float c = ct[s * 32 + d], sn = st[s * 32 + d];
            float lo = acc[mi][ni][i], hi = acc[mi][ni + 2][i];
            ob[d]      = f2bf(lo * c - hi * sn);
            ob[d + 32] = f2bf(hi * c + lo * sn);
          }
        } else {
#pragma unroll
          for (int ni = 0; ni < 4; ni++) ob[ni * 16 + lr16] = f2bf(acc[mi][ni][i]);
        }
      }
  }
}

__global__ __launch_bounds__(256) void proj_kernel(
    const u16* __restrict__ qb, const u16* __restrict__ kb, const u16* __restrict__ vb,
    const u16* __restrict__ wq, const u16* __restrict__ wk, const u16* __restrict__ wv,
    u16* __restrict__ Qr, u16* __restrict__ Kr, u16* __restrict__ Vr,
    const float* __restrict__ ct, const float* __restrict__ st) {
  __shared__ u16 At[128 * 64];
  __shared__ u16 Bt[128 * 64];
  int w = blockIdx.y;
  const u16* A = (w == 0) ? qb : (w == 1) ? kb : vb;
  const u16* W = (w == 0) ? wq : (w == 1) ? wk : wv;
  u16* O = (w == 0) ? Qr : (w == 1) ? Kr : Vr;
  if (w < 2) gemm128_dev<0>(At, Bt, A, W, O, ct, st);
  else       gemm128_dev<1>(At, Bt, A, W, O, ct, st);
}

__global__ __launch_bounds__(256) void out_gemm(const u16* __restrict__ A,
                                                const u16* __restrict__ W,
                                                float* __restrict__ O) {
  __shared__ u16 At[128 * 64];
  __shared__ u16 Bt[128 * 64];
  gemm128_dev<2>(At, Bt, A, W, O, nullptr, nullptr);
}

// ---------------- causal flash attention -----------------------------------
// grid (32 qblocks, 32 bh); 4 waves x 16 q-rows; KBLK=64; Q/K/V in (B,H,S,dk) bf16.
__global__ __launch_bounds__(256) void attn_kernel(const u16* __restrict__ Qr,
                                                   const u16* __restrict__ Kr,
                                                   const u16* __restrict__ Vr,
                                                   u16* __restrict__ ctx) {
  __shared__ u16 Vt[64 * 64];
  __shared__ u16 Pl[64 * 64];
  const int tid = threadIdx.x, lane = tid & 63, wid = tid >> 6;
  const int lg = lane >> 4, lr16 = lane & 15;
  const int bh = blockIdx.y, qb = blockIdx.x;
  const int q0 = qb * 64 + wid * 16;
  const u16* Qb = Qr + (size_t)bh * Ss * DKh;
  const u16* Kb = Kr + (size_t)bh * Ss * DKh;
  const u16* Vb = Vr + (size_t)bh * Ss * DKh;

  short8 qf[2];
#pragma unroll
  for (int ks = 0; ks < 2; ks++)
    qf[ks] = *(const short8*)&Qb[(size_t)(q0 + lr16) * DKh + ks * 32 + lg * 8];

  const f32x4 zero = {0.f, 0.f, 0.f, 0.f};
  float mr[4], lrs[4];
  f32x4 o[4];
#pragma unroll
  for (int i = 0; i < 4; i++) { mr[i] = -1e30f; lrs[i] = 0.f; }
#pragma unroll
  for (int dt = 0; dt < 4; dt++) o[dt] = zero;

  for (int kvb = 0; kvb <= qb; ++kvb) {
    const int kv0 = kvb * 64;
    // stage V tile [64][64] with 32B-chunk swizzle (chunk ^= (row>>3)&3)
#pragma unroll
    for (int c = 0; c < 2; c++) {
      int e = (c * 256 + tid) * 8;
      int row = e >> 6, col = e & 63;
      int ch = col >> 4;
      int sch = ch ^ ((row >> 3) & 3);
      gload16(Vb + (size_t)(kv0 + row) * DKh + sch * 16 + (col & 15),
              &Vt[(c * 256 + wid * 64) * 8]);
    }
    __syncthreads();

    // QK^T : S[16q x 64key], K fragments direct from global (L2-resident)
    f32x4 sacc[4];
#pragma unroll
    for (int ni = 0; ni < 4; ni++) sacc[ni] = zero;
#pragma unroll
    for (int ks = 0; ks < 2; ks++) {
#pragma unroll
      for (int ni = 0; ni < 4; ni++) {
        short8 kf = *(const short8*)&Kb[(size_t)(kv0 + ni * 16 + lr16) * DKh + ks * 32 + lg * 8];
        sacc[ni] = __builtin_amdgcn_mfma_f32_16x16x32_bf16(qf[ks], kf, sacc[ni], 0, 0, 0);
      }
    }

    // scale + causal mask
    float pv[4][4];
#pragma unroll
    for (int ni = 0; ni < 4; ni++) {
      int kk = kv0 + ni * 16 + lr16;
#pragma unroll
      for (int i = 0; i < 4; i++) {
        int q = q0 + lg * 4 + i;
        float vv = sacc[ni][i] * 0.125f;
        pv[ni][i] = (kk > q) ? -1e30f : vv;
      }
    }

    // online softmax (16-lane group = one q row's 16 key-columns per subtile)
#pragma unroll
    for (int i = 0; i < 4; i++) {
      float rm = fmaxf(fmaxf(pv[0][i], pv[1][i]), fmaxf(pv[2][i], pv[3][i]));
      rm = fmaxf(rm, __shfl_xor(rm, 1));
      rm = fmaxf(rm, __shfl_xor(rm, 2));
      rm = fmaxf(rm, __shfl_xor(rm, 4));
      rm = fmaxf(rm, __shfl_xor(rm, 8));
      float mnew = fmaxf(mr[i], rm);
      float corr = __expf(mr[i] - mnew);
      float rs = 0.f;
#pragma unroll
      for (int ni = 0; ni < 4; ni++) {
        float p = __expf(pv[ni][i] - mnew);
        pv[ni][i] = p;
        rs += p;
      }
      rs += __shfl_xor(rs, 1);
      rs += __shfl_xor(rs, 2);
      rs += __shfl_xor(rs, 4);
      rs += __shfl_xor(rs, 8);
      lrs[i] = lrs[i] * corr + rs;
      mr[i] = mnew;
#pragma unroll
      for (int dt = 0; dt < 4; dt++) o[dt][i] *= corr;
    }

    // store P (bf16) to per-wave LDS stripe, 16B-slot XOR swizzle
#pragma unroll
    for (int ni = 0; ni < 4; ni++) {
#pragma unroll
      for (int i = 0; i < 4; i++) {
        int row = wid * 16 + lg * 4 + i;
        int col = ni * 16 + lr16;
        int ps = (col >> 3) ^ (row & 7);
        Pl[row * 64 + ps * 8 + (col & 7)] = f2bf(pv[ni][i]);
      }
    }

    // PV: ctx[16q x 64d] += P[16q x 64k] * V[64k x 64d]
#pragma unroll
    for (int ks = 0; ks < 2; ks++) {
      int prow = wid * 16 + lr16;
      int pslot = (ks * 4 + lg) ^ (prow & 7);
      short8 pa = *(const short8*)&Pl[prow * 64 + pslot * 8];
#pragma unroll
      for (int dt = 0; dt < 4; dt++) {
        int pch = dt ^ lg;  // V chunk swizzle: dt ^ ((row>>3)&3), row>>3 = ks*4+lg
        short8 vf;
#pragma unroll
        for (int j = 0; j < 8; j++) {
          int row = ks * 32 + lg * 8 + j;
          vf[j] = (short)Vt[row * 64 + pch * 16 + lr16];
        }
        o[dt] = __builtin_amdgcn_mfma_f32_16x16x32_bf16(pa, vf, o[dt], 0, 0, 0);
      }
    }
    __syncthreads();
  }

  // normalize and write ctx in (B, S, H*dk) bf16 layout for the output GEMM
  const int b = bh >> 4, h = bh & 15;
#pragma unroll
  for (int i = 0; i < 4; i++) {
    float inv = 1.0f / lrs[i];
    int s = q0 + lg * 4 + i;
    u16* ob = ctx + ((size_t)(b * Ss + s)) * DM + h * DKh;
#pragma unroll
    for (int dt = 0; dt < 4; dt++) ob[dt * 16 + lr16] = f2bf(o[dt][i] * inv);
  }
}

// ---------------- launch ----------------------------------------------------
extern "C" void kernel_launch(void* const* d_in, const int* in_sizes, int n_in,
                              void* d_out, int out_size, void* d_ws, size_t ws_size,
                              hipStream_t stream) {
  (void)in_sizes; (void)n_in; (void)out_size; (void)ws_size;
  const float* q  = (const float*)d_in[0];
  const float* k  = (const float*)d_in[1];
  const float* v  = (const float*)d_in[2];
  // d_in[3] = mask (tril by construction; causality applied analytically)
  const float* Wq = (const float*)d_in[4];
  const float* Wk = (const float*)d_in[5];
  const float* Wv = (const float*)d_in[6];
  const float* Wo = (const float*)d_in[7];
  float* out = (float*)d_out;

  char* p = (char*)d_ws;
  const size_t big = (size_t)Mm * DM * sizeof(u16);   // 8 MiB
  const size_t wsz = (size_t)DM * DM * sizeof(u16);   // 2 MiB
  u16* qb  = (u16*)p; p += big;
  u16* kb  = (u16*)p; p += big;
  u16* vb  = (u16*)p; p += big;
  u16* wqb = (u16*)p; p += wsz;
  u16* wkb = (u16*)p; p += wsz;
  u16* wvb = (u16*)p; p += wsz;
  u16* wob = (u16*)p; p += wsz;
  u16* Qr  = (u16*)p; p += big;
  u16* Kr  = (u16*)p; p += big;
  u16* Vr  = (u16*)p; p += big;
  u16* ctx = (u16*)p; p += big;
  float* ct = (float*)p; p += (size_t)Ss * 32 * sizeof(float);
  float* st = (float*)p; p += (size_t)Ss * 32 * sizeof(float);

  rope_kernel<<<dim3((Ss * 32) / 256), 256, 0, stream>>>(ct, st);
  cvt_kernel<<<dim3((Mm * DM / 4) / 256), 256, 0, stream>>>(q, qb, Mm * DM / 4);
  cvt_kernel<<<dim3((Mm * DM / 4) / 256), 256, 0, stream>>>(k, kb, Mm * DM / 4);
  cvt_kernel<<<dim3((Mm * DM / 4) / 256), 256, 0, stream>>>(v, vb, Mm * DM / 4);
  cvt_kernel<<<dim3((DM * DM / 4) / 256), 256, 0, stream>>>(Wq, wqb, DM * DM / 4);
  cvt_kernel<<<dim3((DM * DM / 4) / 256), 256, 0, stream>>>(Wk, wkb, DM * DM / 4);
  cvt_kernel<<<dim3((DM * DM / 4) / 256), 256, 0, stream>>>(Wv, wvb, DM * DM / 4);
  cvt_kernel<<<dim3((DM * DM / 4) / 256), 256, 0, stream>>>(Wo, wob, DM * DM / 4);

  proj_kernel<<<dim3(256, 3), 256, 0, stream>>>(qb, kb, vb, wqb, wkb, wvb, Qr, Kr, Vr, ct, st);
  attn_kernel<<<dim3(32, 32), 256, 0, stream>>>(Qr, Kr, Vr, ctx);
  out_gemm<<<dim3(256), 256, 0, stream>>>(ctx, wob, out);
}

// Round 3
// 337.311 us; speedup vs baseline: 1.2235x; 1.2235x over previous
//
#include <hip/hip_runtime.h>
#include <stdint.h>
#include <stddef.h>

#define DM 1024
#define NH 16
#define DKh 64
#define Bb 2
#define Ss 2048
#define Mm 4096   // Bb*Ss

typedef unsigned short u16;
typedef __attribute__((ext_vector_type(8))) short short8;
typedef __attribute__((ext_vector_type(4))) float f32x4;

typedef const __attribute__((address_space(1))) void gvoid_t;
typedef __attribute__((address_space(3))) void lvoid_t;

__device__ __forceinline__ void gload16(const void* g, void* l) {
  __builtin_amdgcn_global_load_lds((gvoid_t*)g, (lvoid_t*)l, 16, 0, 0);
}

__device__ __forceinline__ u16 f2bf(float x) {
  unsigned u = __float_as_uint(x);
  unsigned r = (u + 0x7FFFu + ((u >> 16) & 1u)) >> 16;
  return (u16)r;
}

// ---------------- fused prep: fp32->bf16 cvt (q,k,v,4 weights) + RoPE table
__global__ __launch_bounds__(256) void prep_kernel(
    const float* __restrict__ q, const float* __restrict__ k, const float* __restrict__ v,
    const float* __restrict__ Wq, const float* __restrict__ Wk, const float* __restrict__ Wv,
    const float* __restrict__ Wo,
    u16* __restrict__ qb, u16* __restrict__ kb, u16* __restrict__ vb,
    u16* __restrict__ wqb, u16* __restrict__ wkb, u16* __restrict__ wvb, u16* __restrict__ wob,
    float* __restrict__ ct, float* __restrict__ st) {
  const int y = blockIdx.y;
  const int i = blockIdx.x * 256 + threadIdx.x;
  if (y == 7) {
    if (i < Ss * 32) {
      int s = i >> 5, d = i & 31;
      float inv = expf(-(float)d * (9.210340371976184f / 32.0f)); // ln(10000)/32
      float a = (float)s * inv;
      ct[i] = cosf(a);
      st[i] = sinf(a);
    }
    return;
  }
  const float* src; u16* dst; int n4;
  if (y == 0)      { src = q;  dst = qb;  n4 = Mm * DM / 4; }
  else if (y == 1) { src = k;  dst = kb;  n4 = Mm * DM / 4; }
  else if (y == 2) { src = v;  dst = vb;  n4 = Mm * DM / 4; }
  else if (y == 3) { src = Wq; dst = wqb; n4 = DM * DM / 4; }
  else if (y == 4) { src = Wk; dst = wkb; n4 = DM * DM / 4; }
  else if (y == 5) { src = Wv; dst = wvb; n4 = DM * DM / 4; }
  else             { src = Wo; dst = wob; n4 = DM * DM / 4; }
  if (i >= n4) return;
  float4 vv = ((const float4*)src)[i];
  ushort4 ov;
  ov.x = f2bf(vv.x); ov.y = f2bf(vv.y); ov.z = f2bf(vv.z); ov.w = f2bf(vv.w);
  ((ushort4*)dst)[i] = ov;
}

// ---------------- 128x128 bf16 MFMA GEMM body ------------------------------
// C[m,n] = sum_k A[m,k] * W[n,k]   (A: Mx1024 row-major, W: 1024x1024 row-major)
// MODE 0: bf16 out to (B,H,S,dk) with RoPE
// MODE 1: bf16 out TRANSPOSED to (B,H,dk,S)   (for V: PV B-fragment = 16B row)
// MODE 2: fp32 row-major out.
template <int MODE>
__device__ void gemm128_dev(u16* At, u16* Bt,
                            const u16* __restrict__ A, const u16* __restrict__ W,
                            void* __restrict__ O,
                            const float* __restrict__ ct, const float* __restrict__ st) {
  const int tid = threadIdx.x, lane = tid & 63, wid = tid >> 6;
  const int tm = blockIdx.x >> 3, tn = blockIdx.x & 7;
  const int wr = wid >> 1, wc = wid & 1;
  const int lg = lane >> 4, lr16 = lane & 15;
  const f32x4 zero = {0.f, 0.f, 0.f, 0.f};
  f32x4 acc[4][4];
#pragma unroll
  for (int a = 0; a < 4; a++)
#pragma unroll
    for (int b = 0; b < 4; b++) acc[a][b] = zero;

  const u16* Ab = A + (size_t)tm * 128 * DM;
  const u16* Wb = W + (size_t)tn * 128 * DM;

  for (int kt = 0; kt < 16; kt++) {
    const int k0 = kt * 64;
    // stage A and W tiles: [128][64] bf16, 16B-slot XOR swizzle (slot ^= row&7)
#pragma unroll
    for (int c = 0; c < 4; c++) {
      int e = (c * 256 + tid) * 8;
      int row = e >> 6, slot = (e >> 3) & 7;
      int ss = slot ^ (row & 7);
      gload16(Ab + (size_t)row * DM + k0 + ss * 8, &At[(c * 256 + wid * 64) * 8]);
    }
#pragma unroll
    for (int c = 0; c < 4; c++) {
      int e = (c * 256 + tid) * 8;
      int row = e >> 6, slot = (e >> 3) & 7;
      int ss = slot ^ (row & 7);
      gload16(Wb + (size_t)row * DM + k0 + ss * 8, &Bt[(c * 256 + wid * 64) * 8]);
    }
    __syncthreads();
#pragma unroll
    for (int kk = 0; kk < 2; kk++) {
      short8 af[4], bfr[4];
#pragma unroll
      for (int mi = 0; mi < 4; mi++) {
        int row = wr * 64 + mi * 16 + lr16;
        int ps = (kk * 4 + lg) ^ (row & 7);
        af[mi] = *(const short8*)&At[row * 64 + ps * 8];
      }
#pragma unroll
      for (int ni = 0; ni < 4; ni++) {
        int row = wc * 64 + ni * 16 + lr16;
        int ps = (kk * 4 + lg) ^ (row & 7);
        bfr[ni] = *(const short8*)&Bt[row * 64 + ps * 8];
      }
#pragma unroll
      for (int mi = 0; mi < 4; mi++)
#pragma unroll
        for (int ni = 0; ni < 4; ni++)
          acc[mi][ni] = __builtin_amdgcn_mfma_f32_16x16x32_bf16(af[mi], bfr[ni], acc[mi][ni], 0, 0, 0);
    }
    __syncthreads();
  }

  // epilogue. C layout: col = lane&15, row = (lane>>4)*4 + i
  if (MODE == 2) {
    float* Out = (float*)O;
#pragma unroll
    for (int mi = 0; mi < 4; mi++)
#pragma unroll
      for (int i = 0; i < 4; i++) {
        int m = tm * 128 + wr * 64 + mi * 16 + lg * 4 + i;
        float* orow = Out + (size_t)m * DM + tn * 128 + wc * 64;
#pragma unroll
        for (int ni = 0; ni < 4; ni++) orow[ni * 16 + lr16] = acc[mi][ni][i];
      }
  } else if (MODE == 1) {
    // V^T: (B, H, dk, S). head h = tn*2+wc; d = ni*16+lr16; s = m index.
    u16* Out = (u16*)O;
    const int h = tn * 2 + wc;
#pragma unroll
    for (int mi = 0; mi < 4; mi++) {
      int s0 = tm * 128 + wr * 64 + mi * 16 + lg * 4;
      int b = s0 >> 11, s = s0 & 2047;
#pragma unroll
      for (int ni = 0; ni < 4; ni++) {
        int d = ni * 16 + lr16;
        u16* ob = Out + (((size_t)(b * NH + h)) * DKh + d) * Ss + s;
        ushort4 pk;
        pk.x = f2bf(acc[mi][ni][0]); pk.y = f2bf(acc[mi][ni][1]);
        pk.z = f2bf(acc[mi][ni][2]); pk.w = f2bf(acc[mi][ni][3]);
        *(ushort4*)ob = pk;
      }
    }
  } else {
    u16* Out = (u16*)O;
    const int h = tn * 2 + wc;  // head index (64-wide wave block == one head)
#pragma unroll
    for (int mi = 0; mi < 4; mi++)
#pragma unroll
      for (int i = 0; i < 4; i++) {
        int m = tm * 128 + wr * 64 + mi * 16 + lg * 4 + i;
        int b = m >> 11, s = m & 2047;
        u16* ob = Out + (((size_t)(b * NH + h)) * Ss + s) * DKh;
#pragma unroll
        for (int ni = 0; ni < 2; ni++) {
          int d = ni * 16 + lr16;  // in [0,32)
          float c = ct[s * 32 + d], sn = st[s * 32 + d];
          float lo = acc[mi][ni][i], hi = acc[mi][ni + 2][i];
          ob[d]      = f2bf(lo * c - hi * sn);
          ob[d + 32] = f2bf(hi * c + lo * sn);
        }
      }
  }
}

__global__ __launch_bounds__(256) void proj_kernel(
    const u16* __restrict__ qb, const u16* __restrict__ kb, const u16* __restrict__ vb,
    const u16* __restrict__ wq, const u16* __restrict__ wk, const u16* __restrict__ wv,
    u16* __restrict__ Qr, u16* __restrict__ Kr, u16* __restrict__ Vt,
    const float* __restrict__ ct, const float* __restrict__ st) {
  __shared__ u16 At[128 * 64];
  __shared__ u16 Bt[128 * 64];
  int w = blockIdx.y;
  const u16* A = (w == 0) ? qb : (w == 1) ? kb : vb;
  const u16* W = (w == 0) ? wq : (w == 1) ? wk : wv;
  u16* O = (w == 0) ? Qr : (w == 1) ? Kr : Vt;
  if (w < 2) gemm128_dev<0>(At, Bt, A, W, O, ct, st);
  else       gemm128_dev<1>(At, Bt, A, W, O, ct, st);
}

__global__ __launch_bounds__(256) void out_gemm(const u16* __restrict__ A,
                                                const u16* __restrict__ W,
                                                float* __restrict__ O) {
  __shared__ u16 At[128 * 64];
  __shared__ u16 Bt[128 * 64];
  gemm128_dev<2>(At, Bt, A, W, O, nullptr, nullptr);
}

// ---------------- causal flash attention (barrier-free) --------------------
// grid (32 bh, 32 qtiles reversed); 4 waves x 16 q-rows; KBLK=64.
// Q,K in (B,H,S,dk); V TRANSPOSED in (B,H,dk,S). K/V fragments straight from
// global (L2-resident, ~512KB per head, same-bh blocks share an XCD since
// 32 % 8 == 0). P goes through a per-wave LDS stripe -> NO __syncthreads.
__global__ __launch_bounds__(256) void attn_kernel(const u16* __restrict__ Qr,
                                                   const u16* __restrict__ Kr,
                                                   const u16* __restrict__ Vt,
                                                   u16* __restrict__ ctx) {
  __shared__ u16 Pl[64 * 64];
  const int tid = threadIdx.x, lane = tid & 63, wid = tid >> 6;
  const int lg = lane >> 4, lr16 = lane & 15;
  const int bh = blockIdx.x;
  const int qt = 31 - blockIdx.y;           // longest tiles dispatch first
  const int qw0 = qt * 64 + wid * 16;
  const u16* Qb = Qr + (size_t)bh * Ss * DKh;
  const u16* Kb = Kr + (size_t)bh * Ss * DKh;
  const u16* Vb = Vt + (size_t)bh * DKh * Ss;

  short8 qf[2];
#pragma unroll
  for (int ks = 0; ks < 2; ks++)
    qf[ks] = *(const short8*)&Qb[(size_t)(qw0 + lr16) * DKh + ks * 32 + lg * 8];

  const f32x4 zero = {0.f, 0.f, 0.f, 0.f};
  float mr[4], ls[4];
  f32x4 o[4];
#pragma unroll
  for (int i = 0; i < 4; i++) { mr[i] = -1e30f; ls[i] = 0.f; }
#pragma unroll
  for (int dt = 0; dt < 4; dt++) o[dt] = zero;

  const int nkv = qt + 1;
  for (int kvb = 0; kvb < nkv; ++kvb) {
    const int kv0 = kvb * 64;

    // QK^T : S[16q x 64key], K fragments 16B from global
    f32x4 sacc[4];
#pragma unroll
    for (int ni = 0; ni < 4; ni++) sacc[ni] = zero;
#pragma unroll
    for (int ks = 0; ks < 2; ks++) {
#pragma unroll
      for (int ni = 0; ni < 4; ni++) {
        short8 kf = *(const short8*)&Kb[(size_t)(kv0 + ni * 16 + lr16) * DKh + ks * 32 + lg * 8];
        sacc[ni] = __builtin_amdgcn_mfma_f32_16x16x32_bf16(qf[ks], kf, sacc[ni], 0, 0, 0);
      }
    }

    // scale + causal mask (wave-uniform skip for interior tiles)
    float pv[4][4];
#pragma unroll
    for (int ni = 0; ni < 4; ni++)
#pragma unroll
      for (int i = 0; i < 4; i++) pv[ni][i] = sacc[ni][i] * 0.125f;
    if (kv0 + 63 > qw0) {
#pragma unroll
      for (int ni = 0; ni < 4; ni++) {
        int kk = kv0 + ni * 16 + lr16;
#pragma unroll
        for (int i = 0; i < 4; i++)
          if (kk > qw0 + lg * 4 + i) pv[ni][i] = -1e30f;
      }
    }

    // online softmax (reduce across the 16 lanes holding one q-row)
#pragma unroll
    for (int i = 0; i < 4; i++) {
      float rm = fmaxf(fmaxf(pv[0][i], pv[1][i]), fmaxf(pv[2][i], pv[3][i]));
      rm = fmaxf(rm, __shfl_xor(rm, 1));
      rm = fmaxf(rm, __shfl_xor(rm, 2));
      rm = fmaxf(rm, __shfl_xor(rm, 4));
      rm = fmaxf(rm, __shfl_xor(rm, 8));
      float mnew = fmaxf(mr[i], rm);
      float corr = __expf(mr[i] - mnew);
      float rs = 0.f;
#pragma unroll
      for (int ni = 0; ni < 4; ni++) {
        float p = __expf(pv[ni][i] - mnew);
        pv[ni][i] = p;
        rs += p;
      }
      rs += __shfl_xor(rs, 1);
      rs += __shfl_xor(rs, 2);
      rs += __shfl_xor(rs, 4);
      rs += __shfl_xor(rs, 8);
      ls[i] = ls[i] * corr + rs;
      mr[i] = mnew;
#pragma unroll
      for (int dt = 0; dt < 4; dt++) o[dt][i] *= corr;
    }

    // store P (bf16) to per-wave LDS stripe, 16B-slot XOR swizzle
#pragma unroll
    for (int ni = 0; ni < 4; ni++) {
#pragma unroll
      for (int i = 0; i < 4; i++) {
        int row = wid * 16 + lg * 4 + i;
        int col = ni * 16 + lr16;
        int ps = (col >> 3) ^ (row & 7);
        Pl[row * 64 + ps * 8 + (col & 7)] = f2bf(pv[ni][i]);
      }
    }

    // PV: ctx[16q x 64d] += P[16q x 64k] * V[64k x 64d]; V^T rows from global
    const int prow = wid * 16 + lr16;
#pragma unroll
    for (int ks = 0; ks < 2; ks++) {
      const int pslot = (ks * 4 + lg) ^ (prow & 7);
      short8 pa = *(const short8*)&Pl[prow * 64 + pslot * 8];
      const u16* vrow = Vb + kv0 + ks * 32 + lg * 8;
#pragma unroll
      for (int dt = 0; dt < 4; dt++) {
        short8 vf = *(const short8*)&vrow[(size_t)(dt * 16 + lr16) * Ss];
        o[dt] = __builtin_amdgcn_mfma_f32_16x16x32_bf16(pa, vf, o[dt], 0, 0, 0);
      }
    }
  }

  // normalize and write ctx in (B, S, H*dk) bf16 layout for the output GEMM
  const int b = bh >> 4, h = bh & 15;
#pragma unroll
  for (int i = 0; i < 4; i++) {
    float inv = 1.0f / ls[i];
    int s = qt * 64 + wid * 16 + lg * 4 + i;
    u16* ob = ctx + ((size_t)(b * Ss + s)) * DM + h * DKh;
#pragma unroll
    for (int dt = 0; dt < 4; dt++) ob[dt * 16 + lr16] = f2bf(o[dt][i] * inv);
  }
}

// ---------------- launch ----------------------------------------------------
extern "C" void kernel_launch(void* const* d_in, const int* in_sizes, int n_in,
                              void* d_out, int out_size, void* d_ws, size_t ws_size,
                              hipStream_t stream) {
  (void)in_sizes; (void)n_in; (void)out_size; (void)ws_size;
  const float* q  = (const float*)d_in[0];
  const float* k  = (const float*)d_in[1];
  const float* v  = (const float*)d_in[2];
  // d_in[3] = mask (tril by construction; causality applied analytically)
  const float* Wq = (const float*)d_in[4];
  const float* Wk = (const float*)d_in[5];
  const float* Wv = (const float*)d_in[6];
  const float* Wo = (const float*)d_in[7];
  float* out = (float*)d_out;

  char* p = (char*)d_ws;
  const size_t big = (size_t)Mm * DM * sizeof(u16);   // 8 MiB
  const size_t wsz = (size_t)DM * DM * sizeof(u16);   // 2 MiB
  u16* qb  = (u16*)p; p += big;
  u16* kb  = (u16*)p; p += big;
  u16* vb  = (u16*)p; p += big;
  u16* wqb = (u16*)p; p += wsz;
  u16* wkb = (u16*)p; p += wsz;
  u16* wvb = (u16*)p; p += wsz;
  u16* wob = (u16*)p; p += wsz;
  u16* Qr  = (u16*)p; p += big;
  u16* Kr  = (u16*)p; p += big;
  u16* Vt  = (u16*)p; p += big;   // V TRANSPOSED (B,H,dk,S)
  u16* ctx = (u16*)p; p += big;
  float* ct = (float*)p; p += (size_t)Ss * 32 * sizeof(float);
  float* st = (float*)p; p += (size_t)Ss * 32 * sizeof(float);

  prep_kernel<<<dim3(4096, 8), 256, 0, stream>>>(q, k, v, Wq, Wk, Wv, Wo,
                                                 qb, kb, vb, wqb, wkb, wvb, wob, ct, st);
  proj_kernel<<<dim3(256, 3), 256, 0, stream>>>(qb, kb, vb, wqb, wkb, wvb, Qr, Kr, Vt, ct, st);
  attn_kernel<<<dim3(32, 32), 256, 0, stream>>>(Qr, Kr, Vt, ctx);
  out_gemm<<<dim3(256), 256, 0, stream>>>(ctx, wob, out);
}